// Round 12
// baseline (799.383 us; speedup 1.0000x reference)
//
#include <hip/hip_runtime.h>
#include <math.h>

#define BCAP2 4608    // bucket capacity (avg 4096 for E=1.6M, NB=391; 8-sigma margin)
#define CHUNK 4096    // edges per part1 block
#define NPB 256       // nodes per prop block group

typedef __attribute__((ext_vector_type(8))) short short8v;   // 8 bf16 (4 VGPRs) MFMA operand
typedef __attribute__((ext_vector_type(4))) float f32x4;     // MFMA accumulator

// G layout: 32 slabs [kblock][node][8cols], kblock = k/8 over 4 slices x 64 cols.
// slice s, col-block cb (8 cols) -> kblock = s*8+cb. Slab stride = npad8 ushorts.

__device__ __forceinline__ unsigned short f2bf(float f) {
    unsigned int u = __builtin_bit_cast(unsigned int, f);
    u += 0x7fff + ((u >> 16) & 1);   // round-to-nearest-even
    return (unsigned short)(u >> 16);
}
__device__ __forceinline__ float bf2f(unsigned short s) {
    return __builtin_bit_cast(float, ((unsigned int)s) << 16);
}
__device__ __forceinline__ void fma4(float4& a, float s, const float4& b) {
    a.x = fmaf(s, b.x, a.x);
    a.y = fmaf(s, b.y, a.y);
    a.z = fmaf(s, b.z, a.z);
    a.w = fmaf(s, b.w, a.w);
}

// ---------------- utility ----------------
__global__ void zero_k(int* __restrict__ p, int n) {
    int i = blockIdx.x * blockDim.x + threadIdx.x;
    int st = gridDim.x * blockDim.x;
    for (; i < n; i += st) p[i] = 0;
}

// ---------------- CSR build, two-level dense-write ----------------
__global__ __launch_bounds__(256) void part1_k(const int* __restrict__ src,
        const int* __restrict__ dst, int* __restrict__ gcnt,
        unsigned int* __restrict__ pairs, int E, int NB) {
    __shared__ int lcnt[512];
    __shared__ int lbase[512];
    __shared__ int lpos[512];
    int tid = threadIdx.x;
    int base = blockIdx.x * CHUNK;
    int m = E - base; if (m > CHUNK) m = CHUNK;
    for (int b = tid; b < NB; b += 256) { lcnt[b] = 0; lpos[b] = 0; }
    __syncthreads();
    for (int i = tid; i < m; i += 256)
        atomicAdd(&lcnt[dst[base + i] >> 8], 1);
    __syncthreads();
    for (int b = tid; b < NB; b += 256)
        lbase[b] = (lcnt[b] > 0) ? atomicAdd(&gcnt[b], lcnt[b]) : 0;
    __syncthreads();
    for (int i = tid; i < m; i += 256) {
        int s = src[base + i], d = dst[base + i];
        int b = d >> 8;
        int p = atomicAdd(&lpos[b], 1);
        int idx = lbase[b] + p;
        if (idx < BCAP2)
            pairs[(size_t)b * BCAP2 + idx] = (unsigned int)s | ((unsigned int)(d & 255) << 17);
    }
}

__global__ __launch_bounds__(512) void bscan_k(const int* __restrict__ gcnt,
        int* __restrict__ bbase, int* __restrict__ rowp, int NB, int E, int n) {
    __shared__ int buf[512];
    int tid = threadIdx.x;
    int v = (tid < NB) ? (gcnt[tid] > BCAP2 ? BCAP2 : gcnt[tid]) : 0;
    buf[tid] = v;
    __syncthreads();
    int x = v;
    for (int off = 1; off < 512; off <<= 1) {
        int t = (tid >= off) ? buf[tid - off] : 0;
        __syncthreads();
        x += t;
        buf[tid] = x;
        __syncthreads();
    }
    if (tid < NB) bbase[tid] = x - v;
    if (tid == 0) rowp[n] = E;
}

__global__ __launch_bounds__(256) void csr2_k(const int* __restrict__ gcnt,
        const unsigned int* __restrict__ pairs, const int* __restrict__ bbase,
        int* __restrict__ rowp, int* __restrict__ colb, float* __restrict__ dinv, int n) {
    int b = blockIdx.x;
    int tid = threadIdx.x;
    int cntb = gcnt[b]; if (cntb > BCAP2) cntb = BCAP2;
    const unsigned int* pb = pairs + (size_t)b * BCAP2;
    __shared__ int c[256];
    __shared__ int sc[256];
    __shared__ int lpos[256];
    c[tid] = 0; lpos[tid] = 0;
    __syncthreads();
    for (int i = tid; i < cntb; i += 256)
        atomicAdd(&c[pb[i] >> 17], 1);
    __syncthreads();
    int v = c[tid];
    sc[tid] = v;
    __syncthreads();
    int x = v;
    for (int off = 1; off < 256; off <<= 1) {
        int t = (tid >= off) ? sc[tid - off] : 0;
        __syncthreads();
        x += t;
        sc[tid] = x;
        __syncthreads();
    }
    int ex = x - v;                 // exclusive within-bucket start
    sc[tid] = ex;
    int node = b * 256 + tid;
    if (node < n) {
        rowp[node] = bbase[b] + ex;
        dinv[node] = 1.0f / sqrtf((float)(v > 1 ? v : 1));
    }
    __syncthreads();                // sc (exclusive) visible to all
    for (int i = tid; i < cntb; i += 256) {
        unsigned int pk = pb[i];
        int j = pk >> 17;
        int p = atomicAdd(&lpos[j], 1);
        colb[bbase[b] + sc[j] + p] = (int)(pk & 0x1FFFF);
    }
}

// ---------------- fused 2-layer MLP; emits g0 = h2*dinv as bf16 hi/lo into slab layout ----------------
__global__ __launch_bounds__(256) void mlp_k(const float* __restrict__ x,
        const float* __restrict__ W1, const float* __restrict__ b1,
        const float* __restrict__ W2, const float* __restrict__ b2,
        const float* __restrict__ dinv,
        unsigned short* __restrict__ Ghi, unsigned short* __restrict__ Glo,
        int n, int ntiles, size_t npad8) {
    __shared__ float Ws1[64 * 64];   // 16 KB, [k][j]
    __shared__ float Ws2[64 * 64];   // 16 KB
    __shared__ float xT[64 * 68];    // 17.4 KB, [k][node], stride 68 (16B-aligned rows)
    int tid = threadIdx.x;
    int ti = tid >> 4, tj = tid & 15;
    for (int idx = tid; idx < 4096; idx += 256) { Ws1[idx] = W1[idx]; Ws2[idx] = W2[idx]; }
    float4 b1v = *(const float4*)&b1[4 * tj];
    float4 b2v = *(const float4*)&b2[4 * tj];
    int kb = tj >> 1;                  // slice-0 kblock for cols 4*tj..4*tj+3
    int off = (tj & 1) * 4;

    for (int g = blockIdx.x; g < ntiles; g += gridDim.x) {
        int base = g * 64;
        __syncthreads();   // xT free of previous tile's readers (also covers Ws staging on iter 0)
        for (int it = 0; it < 4; it++) {
            int node = ti + it * 16;
            int gn = base + node;
            float4 v = make_float4(0.f, 0.f, 0.f, 0.f);
            if (gn < n) v = *(const float4*)&x[(size_t)gn * 64 + 4 * tj];
            xT[(4 * tj + 0) * 68 + node] = v.x;
            xT[(4 * tj + 1) * 68 + node] = v.y;
            xT[(4 * tj + 2) * 68 + node] = v.z;
            xT[(4 * tj + 3) * 68 + node] = v.w;
        }
        __syncthreads();

        // layer 1
        float4 a0 = b1v, a1 = b1v, a2 = b1v, a3 = b1v;
        #pragma unroll 8
        for (int k = 0; k < 64; k++) {
            float4 xv = *(const float4*)&xT[k * 68 + 4 * ti];
            float4 wv = *(const float4*)&Ws1[k * 64 + 4 * tj];
            fma4(a0, xv.x, wv); fma4(a1, xv.y, wv); fma4(a2, xv.z, wv); fma4(a3, xv.w, wv);
        }
        __syncthreads();
        {
            int hb = (4 * tj) * 68 + 4 * ti;
            xT[hb + 0 * 68 + 0] = fmaxf(a0.x, 0.f);
            xT[hb + 1 * 68 + 0] = fmaxf(a0.y, 0.f);
            xT[hb + 2 * 68 + 0] = fmaxf(a0.z, 0.f);
            xT[hb + 3 * 68 + 0] = fmaxf(a0.w, 0.f);
            xT[hb + 0 * 68 + 1] = fmaxf(a1.x, 0.f);
            xT[hb + 1 * 68 + 1] = fmaxf(a1.y, 0.f);
            xT[hb + 2 * 68 + 1] = fmaxf(a1.z, 0.f);
            xT[hb + 3 * 68 + 1] = fmaxf(a1.w, 0.f);
            xT[hb + 0 * 68 + 2] = fmaxf(a2.x, 0.f);
            xT[hb + 1 * 68 + 2] = fmaxf(a2.y, 0.f);
            xT[hb + 2 * 68 + 2] = fmaxf(a2.z, 0.f);
            xT[hb + 3 * 68 + 2] = fmaxf(a2.w, 0.f);
            xT[hb + 0 * 68 + 3] = fmaxf(a3.x, 0.f);
            xT[hb + 1 * 68 + 3] = fmaxf(a3.y, 0.f);
            xT[hb + 2 * 68 + 3] = fmaxf(a3.z, 0.f);
            xT[hb + 3 * 68 + 3] = fmaxf(a3.w, 0.f);
        }
        __syncthreads();

        // layer 2
        a0 = b2v; a1 = b2v; a2 = b2v; a3 = b2v;
        #pragma unroll 8
        for (int k = 0; k < 64; k++) {
            float4 xv = *(const float4*)&xT[k * 68 + 4 * ti];
            float4 wv = *(const float4*)&Ws2[k * 64 + 4 * tj];
            fma4(a0, xv.x, wv); fma4(a1, xv.y, wv); fma4(a2, xv.z, wv); fma4(a3, xv.w, wv);
        }
        int gn0 = base + 4 * ti;
#define STORE_ROW(ai, ii)                                                                  \
        {                                                                                  \
            int gn = gn0 + (ii);                                                           \
            if (gn < n) {                                                                  \
                float dg = dinv[gn];                                                       \
                float g0 = fmaxf(ai.x, 0.f) * dg, g1 = fmaxf(ai.y, 0.f) * dg;              \
                float g2 = fmaxf(ai.z, 0.f) * dg, g3 = fmaxf(ai.w, 0.f) * dg;              \
                ushort4 hv, lv;                                                            \
                hv.x = f2bf(g0); lv.x = f2bf(g0 - bf2f(hv.x));                             \
                hv.y = f2bf(g1); lv.y = f2bf(g1 - bf2f(hv.y));                             \
                hv.z = f2bf(g2); lv.z = f2bf(g2 - bf2f(hv.z));                             \
                hv.w = f2bf(g3); lv.w = f2bf(g3 - bf2f(hv.w));                             \
                *(ushort4*)&Ghi[(size_t)kb * npad8 + (size_t)gn * 8 + off] = hv;           \
                *(ushort4*)&Glo[(size_t)kb * npad8 + (size_t)gn * 8 + off] = lv;           \
            }                                                                              \
        }
        STORE_ROW(a0, 0) STORE_ROW(a1, 1) STORE_ROW(a2, 2) STORE_ROW(a3, 3)
#undef STORE_ROW
    }
}

// ---------------- fold thetas into Wm1; emit split-bf16 TRANSPOSED weights ----------------
__global__ void wm1p_k(const float* __restrict__ thetas, const float* __restrict__ Wm1,
                       unsigned short* __restrict__ Wth, unsigned short* __restrict__ Wtl) {
    int idx = blockIdx.x * blockDim.x + threadIdx.x;   // 16384 total
    if (idx >= 16384) return;
    int j = idx & 63;
    int q = idx >> 6;      // k*64 + h
    int k = q >> 6;
    int hh = q & 63;
    float a = 0.f;
    for (int c = 0; c < 4; c++) a += thetas[c * 4 + k] * Wm1[(c * 64 + hh) * 64 + j];
    unsigned short hi = f2bf(a);
    float r = a - bf2f(hi);
    Wth[j * 256 + q] = hi;
    Wtl[j * 256 + q] = f2bf(r);
}

// ---------------- propagation, column-partitioned (XCD-slab) ----------------
// block: cb = blockIdx.x & 7 (8 cols each), group = blockIdx.x >> 3 (NPB nodes).
// wave = 1 node; lane = (es=lane>>3, c=lane&7): 8 edges per gather instruction.
// g_out = g_in - dinv^2 * sum_src ghi[src]; hi/lo bf16 pair.
__global__ __launch_bounds__(256) void prop_k(
        const unsigned short* __restrict__ GhiSlabIn,   // Ghi + s*8*npad8
        const unsigned short* __restrict__ GloSlabIn,   // Glo + s*8*npad8
        unsigned short* __restrict__ GhiSlabOut,        // Ghi + (s+1)*8*npad8
        unsigned short* __restrict__ GloSlabOut,        // Glo + (s+1)*8*npad8
        const int* __restrict__ rowp, const int* __restrict__ colb,
        const float* __restrict__ dinv, int n, size_t npad8, int writeLo) {
    int cb = blockIdx.x & 7;
    int grp = blockIdx.x >> 3;
    const unsigned short* Gin = GhiSlabIn + (size_t)cb * npad8;
    const unsigned short* Lin = GloSlabIn + (size_t)cb * npad8;
    unsigned short* Hout = GhiSlabOut + (size_t)cb * npad8;
    unsigned short* Lout = GloSlabOut + (size_t)cb * npad8;
    int lane = threadIdx.x & 63;
    int wv = threadIdx.x >> 6;
    int c = lane & 7, es = lane >> 3;
    int nb = grp * NPB;
    int ne = nb + NPB; if (ne > n) ne = n;
    for (int nd = nb + wv; nd < ne; nd += 4) {
        int beg = rowp[nd], end = rowp[nd + 1];
        float acc = 0.f;
        int e = beg + es;
        for (; e + 8 < end; e += 16) {
            int s0 = colb[e], s1 = colb[e + 8];
            float f0 = bf2f(Gin[(size_t)s0 * 8 + c]);
            float f1 = bf2f(Gin[(size_t)s1 * 8 + c]);
            acc += f0 + f1;
        }
        if (e < end) acc += bf2f(Gin[(size_t)colb[e] * 8 + c]);
        acc += __shfl_xor(acc, 8);
        acc += __shfl_xor(acc, 16);
        acc += __shfl_xor(acc, 32);
        if (es == 0) {
            float dg = dinv[nd];
            float gown = bf2f(Gin[(size_t)nd * 8 + c]) + bf2f(Lin[(size_t)nd * 8 + c]);
            float go = gown - dg * dg * acc;
            unsigned short hi = f2bf(go);
            Hout[(size_t)nd * 8 + c] = hi;
            if (writeLo) Lout[(size_t)nd * 8 + c] = f2bf(go - bf2f(hi));
        }
    }
}

// ---------------- final (MFMA): out = relu(s*(G_row @ (Whi+Wlo)) + bm1) @ Wm2 + bm2 ----------------
// 512 threads = 8 waves = 2 row-halves x 4 col-tiles; one 128-row tile per block.
// A rows gathered from slab layout: k-index ks*32+rgrp*8+j -> kblock ks*4+rgrp, 16B granule.
__global__ __launch_bounds__(512, 4) void final_k(const unsigned short* __restrict__ Ghi,
        const float* __restrict__ dinv,
        const unsigned short* __restrict__ Wth, const unsigned short* __restrict__ Wtl,
        const float* __restrict__ bm1, const float* __restrict__ Wm2,
        const float* __restrict__ bm2, float* __restrict__ out, int n, size_t npad8) {
    __shared__ float Lp[4][128][2];   // per-col-tile partial (o0,o1) per row
    int tid = threadIdx.x;
    int w = tid >> 6, l = tid & 63;
    int cw = w & 3, half = w >> 2;
    int colg = 16 * cw + (l & 15);    // global output column 0..63
    int krow = (l >> 4) * 8;          // k-offset within a 32-wide k-step
    int rgrp = l >> 4;

    // preload B fragments: b[ks] covers k in [ks*32, ks*32+32)
    short8v bhi[8], blo[8];
    #pragma unroll
    for (int ks = 0; ks < 8; ks++) {
        bhi[ks] = *(const short8v*)&Wth[colg * 256 + ks * 32 + krow];
        blo[ks] = *(const short8v*)&Wtl[colg * 256 + ks * 32 + krow];
    }
    float bm1c = bm1[colg];
    float w2x = Wm2[colg * 2 + 0], w2y = Wm2[colg * 2 + 1];

    for (int rt = 0; rt < 4; rt++) {
        int r = blockIdx.x * 128 + half * 64 + rt * 16 + (l & 15);
        size_t rbase = (size_t)rgrp * npad8 + (size_t)r * 8;
        f32x4 acc = {0.f, 0.f, 0.f, 0.f};
        #pragma unroll
        for (int ks = 0; ks < 8; ks++) {
            short8v a = *(const short8v*)&Ghi[rbase + (size_t)(ks * 4) * npad8];
            acc = __builtin_amdgcn_mfma_f32_16x16x32_bf16(a, bhi[ks], acc, 0, 0, 0);
            acc = __builtin_amdgcn_mfma_f32_16x16x32_bf16(a, blo[ks], acc, 0, 0, 0);
        }
        // epilogue: C layout col=lane&15, row=(lane>>4)*4+reg (verified m89/m91)
        #pragma unroll
        for (int i = 0; i < 4; i++) {
            int rl = half * 64 + rt * 16 + (l >> 4) * 4 + i;     // row within 128-tile
            int grow = blockIdx.x * 128 + rl;
            float s = (grow < n) ? (1.0f / dinv[grow]) : 0.f;
            float h = fmaxf(fmaf(acc[i], s, bm1c), 0.f);
            float q0 = h * w2x, q1 = h * w2y;
            q0 += __shfl_xor(q0, 1); q1 += __shfl_xor(q1, 1);
            q0 += __shfl_xor(q0, 2); q1 += __shfl_xor(q1, 2);
            q0 += __shfl_xor(q0, 4); q1 += __shfl_xor(q1, 4);
            q0 += __shfl_xor(q0, 8); q1 += __shfl_xor(q1, 8);
            if ((l & 15) == 0) {
                Lp[cw][rl][0] = q0;
                Lp[cw][rl][1] = q1;
            }
        }
    }
    __syncthreads();
    if (tid < 256) {
        int r = tid >> 1, ch = tid & 1;
        int grow = blockIdx.x * 128 + r;
        if (grow < n) {
            float v = Lp[0][r][ch] + Lp[1][r][ch] + Lp[2][r][ch] + Lp[3][r][ch] + bm2[ch];
            out[grow * 2 + ch] = v;
        }
    }
}

extern "C" void kernel_launch(void* const* d_in, const int* in_sizes, int n_in,
                              void* d_out, int out_size, void* d_ws, size_t ws_size,
                              hipStream_t stream) {
    const float* x      = (const float*)d_in[0];
    const int*   src    = (const int*)d_in[1];
    const int*   dst    = (const int*)d_in[2];
    const float* thetas = (const float*)d_in[3];
    const float* W1     = (const float*)d_in[4];
    const float* b1     = (const float*)d_in[5];
    const float* W2     = (const float*)d_in[6];
    const float* b2     = (const float*)d_in[7];
    const float* Wm1    = (const float*)d_in[8];
    const float* bm1    = (const float*)d_in[9];
    const float* Wm2    = (const float*)d_in[10];
    const float* bm2    = (const float*)d_in[11];
    float* out = (float*)d_out;

    int n = in_sizes[0] / 64;
    int E = in_sizes[1];
    int ntiles  = (n + 63) / 64;       // mlp tiles (64 nodes)
    int ntiles2 = (n + 127) / 128;     // final tiles (128 nodes)
    int npad = ntiles2 * 128;          // padded node count for slabs
    size_t npad8 = (size_t)npad * 8;   // slab stride (ushorts)
    int NB = (n + 255) / 256;          // coarse buckets (NB <= 512, n <= 131072)

    // workspace layout:
    unsigned short* Glo = (unsigned short*)d_ws;      // 24 slabs (slices 0..2) ~38.5 MB
    float* dinv  = (float*)(Glo + 24 * npad8);        // n
    int*   rowp  = (int*)(dinv + n);                  // n+1
    int*   colb  = rowp + (n + 1);                    // E
    size_t woff = (((size_t)(colb + E) - (size_t)d_ws) + 15) & ~(size_t)15;
    unsigned short* Wth = (unsigned short*)((char*)d_ws + woff);
    unsigned short* Wtl = Wth + 16384;
    int*   gcnt  = (int*)(Wtl + 16384);               // NB
    int*   bbase = gcnt + NB;                         // NB
    // union region (256B aligned): pairs (part1..csr2) then Ghi (mlp onward)
    size_t uoff = (((size_t)(bbase + NB) - (size_t)d_ws) + 255) & ~(size_t)255;
    unsigned int*   pairs = (unsigned int*)((char*)d_ws + uoff);      // NB*BCAP2 u32 (~7.2MB)
    unsigned short* Ghi   = (unsigned short*)pairs;                   // 32 slabs (~51.3MB)

    int nchunksP = (E + CHUNK - 1) / CHUNK;

    zero_k<<<4, 256, 0, stream>>>(gcnt, NB);
    part1_k<<<nchunksP, 256, 0, stream>>>(src, dst, gcnt, pairs, E, NB);
    bscan_k<<<1, 512, 0, stream>>>(gcnt, bbase, rowp, NB, E, n);
    csr2_k<<<NB, 256, 0, stream>>>(gcnt, pairs, bbase, rowp, colb, dinv, n);

    // NOTE: Ghi aliases pairs — mlp_k (first Ghi writer) runs only after csr2_k (last pairs reader)
    mlp_k<<<768, 256, 0, stream>>>(x, W1, b1, W2, b2, dinv, Ghi, Glo, n, ntiles, npad8);
    wm1p_k<<<64, 256, 0, stream>>>(thetas, Wm1, Wth, Wtl);

    // hop s: read hi/lo slice s, write slice s+1; cb = blockIdx&7 pins slabs to XCDs
    int pgrid = ((n + NPB - 1) / NPB) * 8;
    prop_k<<<pgrid, 256, 0, stream>>>(
        Ghi + 0 * npad8, Glo + 0 * npad8, Ghi + 8 * npad8, Glo + 8 * npad8,
        rowp, colb, dinv, n, npad8, 1);
    prop_k<<<pgrid, 256, 0, stream>>>(
        Ghi + 8 * npad8, Glo + 8 * npad8, Ghi + 16 * npad8, Glo + 16 * npad8,
        rowp, colb, dinv, n, npad8, 1);
    prop_k<<<pgrid, 256, 0, stream>>>(
        Ghi + 16 * npad8, Glo + 16 * npad8, Ghi + 24 * npad8, Glo,
        rowp, colb, dinv, n, npad8, 0);

    final_k<<<ntiles2, 512, 0, stream>>>(Ghi, dinv, Wth, Wtl, bm1, Wm2, bm2, out, n, npad8);
}

// Round 13
// 290.751 us; speedup vs baseline: 2.7494x; 2.7494x over previous
//
#include <hip/hip_runtime.h>
#include <math.h>

#define TS  256       // Ghi: 4 bf16 slices of 64 per node, k-major (slice k at offset k*64)
#define GS  192       // Glo: 3 bf16 lo-slices of 64 per node (slices 0..2)
#define BCAP2 4608    // bucket capacity (avg 4096 for E=1.6M, NB=391; 8-sigma margin)
#define CHUNK 4096    // edges per part1 block

typedef __attribute__((ext_vector_type(8))) short short8v;   // 8 bf16 (4 VGPRs) MFMA operand
typedef __attribute__((ext_vector_type(4))) float f32x4;     // MFMA accumulator

__device__ __forceinline__ unsigned short f2bf(float f) {
    unsigned int u = __builtin_bit_cast(unsigned int, f);
    u += 0x7fff + ((u >> 16) & 1);   // round-to-nearest-even
    return (unsigned short)(u >> 16);
}
__device__ __forceinline__ float bf2f(unsigned short s) {
    return __builtin_bit_cast(float, ((unsigned int)s) << 16);
}
__device__ __forceinline__ void fma4(float4& a, float s, const float4& b) {
    a.x = fmaf(s, b.x, a.x);
    a.y = fmaf(s, b.y, a.y);
    a.z = fmaf(s, b.z, a.z);
    a.w = fmaf(s, b.w, a.w);
}

// ---------------- utility ----------------
__global__ void zero_k(int* __restrict__ p, int n) {
    int i = blockIdx.x * blockDim.x + threadIdx.x;
    int st = gridDim.x * blockDim.x;
    for (; i < n; i += st) p[i] = 0;
}

// ---------------- CSR build, two-level dense-write ----------------
// part1: chunk-local histogram -> bulk reserve -> dense-ish packed writes.
// bucket = dst>>8 (256 nodes); packed word = src | (dst&255)<<17  (needs n <= 131072)
__global__ __launch_bounds__(256) void part1_k(const int* __restrict__ src,
        const int* __restrict__ dst, int* __restrict__ gcnt,
        unsigned int* __restrict__ pairs, int E, int NB) {
    __shared__ int lcnt[512];
    __shared__ int lbase[512];
    __shared__ int lpos[512];
    int tid = threadIdx.x;
    int base = blockIdx.x * CHUNK;
    int m = E - base; if (m > CHUNK) m = CHUNK;
    for (int b = tid; b < NB; b += 256) { lcnt[b] = 0; lpos[b] = 0; }
    __syncthreads();
    for (int i = tid; i < m; i += 256)
        atomicAdd(&lcnt[dst[base + i] >> 8], 1);
    __syncthreads();
    for (int b = tid; b < NB; b += 256)
        lbase[b] = (lcnt[b] > 0) ? atomicAdd(&gcnt[b], lcnt[b]) : 0;
    __syncthreads();
    for (int i = tid; i < m; i += 256) {
        int s = src[base + i], d = dst[base + i];
        int b = d >> 8;
        int p = atomicAdd(&lpos[b], 1);
        int idx = lbase[b] + p;
        if (idx < BCAP2)
            pairs[(size_t)b * BCAP2 + idx] = (unsigned int)s | ((unsigned int)(d & 255) << 17);
    }
}

// exclusive scan of bucket sizes (NB <= 512), single block of 512; also writes rowp[n]=E
__global__ __launch_bounds__(512) void bscan_k(const int* __restrict__ gcnt,
        int* __restrict__ bbase, int* __restrict__ rowp, int NB, int E, int n) {
    __shared__ int buf[512];
    int tid = threadIdx.x;
    int v = (tid < NB) ? (gcnt[tid] > BCAP2 ? BCAP2 : gcnt[tid]) : 0;
    buf[tid] = v;
    __syncthreads();
    int x = v;
    for (int off = 1; off < 512; off <<= 1) {
        int t = (tid >= off) ? buf[tid - off] : 0;
        __syncthreads();
        x += t;
        buf[tid] = x;
        __syncthreads();
    }
    if (tid < NB) bbase[tid] = x - v;
    if (tid == 0) rowp[n] = E;
}

// csr2: per-bucket histogram + scan + rowp/dinv + dense colb fill (contiguous 16KB window)
__global__ __launch_bounds__(256) void csr2_k(const int* __restrict__ gcnt,
        const unsigned int* __restrict__ pairs, const int* __restrict__ bbase,
        int* __restrict__ rowp, int* __restrict__ colb, float* __restrict__ dinv, int n) {
    int b = blockIdx.x;
    int tid = threadIdx.x;
    int cntb = gcnt[b]; if (cntb > BCAP2) cntb = BCAP2;
    const unsigned int* pb = pairs + (size_t)b * BCAP2;
    __shared__ int c[256];
    __shared__ int sc[256];
    __shared__ int lpos[256];
    c[tid] = 0; lpos[tid] = 0;
    __syncthreads();
    for (int i = tid; i < cntb; i += 256)
        atomicAdd(&c[pb[i] >> 17], 1);
    __syncthreads();
    int v = c[tid];
    sc[tid] = v;
    __syncthreads();
    int x = v;
    for (int off = 1; off < 256; off <<= 1) {
        int t = (tid >= off) ? sc[tid - off] : 0;
        __syncthreads();
        x += t;
        sc[tid] = x;
        __syncthreads();
    }
    int ex = x - v;                 // exclusive within-bucket start
    sc[tid] = ex;
    int node = b * 256 + tid;
    if (node < n) {
        rowp[node] = bbase[b] + ex;
        dinv[node] = 1.0f / sqrtf((float)(v > 1 ? v : 1));
    }
    __syncthreads();                // sc (exclusive) visible to all
    for (int i = tid; i < cntb; i += 256) {
        unsigned int pk = pb[i];
        int j = pk >> 17;
        int p = atomicAdd(&lpos[j], 1);
        colb[bbase[b] + sc[j] + p] = (int)(pk & 0x1FFFF);
    }
}

// ---------------- fused 2-layer MLP, register-tiled; emits g0 = h2*dinv as bf16 hi/lo pair ----------------
__global__ __launch_bounds__(256) void mlp_k(const float* __restrict__ x,
        const float* __restrict__ W1, const float* __restrict__ b1,
        const float* __restrict__ W2, const float* __restrict__ b2,
        const float* __restrict__ dinv,
        unsigned short* __restrict__ Ghi, unsigned short* __restrict__ Glo,
        int n, int ntiles) {
    __shared__ float Ws1[64 * 64];   // 16 KB, [k][j]
    __shared__ float Ws2[64 * 64];   // 16 KB
    __shared__ float xT[64 * 68];    // 17.4 KB, [k][node], stride 68 (16B-aligned rows)
    int tid = threadIdx.x;
    int ti = tid >> 4, tj = tid & 15;
    for (int idx = tid; idx < 4096; idx += 256) { Ws1[idx] = W1[idx]; Ws2[idx] = W2[idx]; }
    float4 b1v = *(const float4*)&b1[4 * tj];
    float4 b2v = *(const float4*)&b2[4 * tj];

    for (int g = blockIdx.x; g < ntiles; g += gridDim.x) {
        int base = g * 64;
        __syncthreads();   // xT free of previous tile's readers (also covers Ws staging on iter 0)
        for (int it = 0; it < 4; it++) {
            int node = ti + it * 16;
            int gn = base + node;
            float4 v = make_float4(0.f, 0.f, 0.f, 0.f);
            if (gn < n) v = *(const float4*)&x[(size_t)gn * 64 + 4 * tj];
            xT[(4 * tj + 0) * 68 + node] = v.x;
            xT[(4 * tj + 1) * 68 + node] = v.y;
            xT[(4 * tj + 2) * 68 + node] = v.z;
            xT[(4 * tj + 3) * 68 + node] = v.w;
        }
        __syncthreads();

        // layer 1
        float4 a0 = b1v, a1 = b1v, a2 = b1v, a3 = b1v;
        #pragma unroll 8
        for (int k = 0; k < 64; k++) {
            float4 xv = *(const float4*)&xT[k * 68 + 4 * ti];
            float4 wv = *(const float4*)&Ws1[k * 64 + 4 * tj];
            fma4(a0, xv.x, wv); fma4(a1, xv.y, wv); fma4(a2, xv.z, wv); fma4(a3, xv.w, wv);
        }
        __syncthreads();
        {
            int hb = (4 * tj) * 68 + 4 * ti;
            xT[hb + 0 * 68 + 0] = fmaxf(a0.x, 0.f);
            xT[hb + 1 * 68 + 0] = fmaxf(a0.y, 0.f);
            xT[hb + 2 * 68 + 0] = fmaxf(a0.z, 0.f);
            xT[hb + 3 * 68 + 0] = fmaxf(a0.w, 0.f);
            xT[hb + 0 * 68 + 1] = fmaxf(a1.x, 0.f);
            xT[hb + 1 * 68 + 1] = fmaxf(a1.y, 0.f);
            xT[hb + 2 * 68 + 1] = fmaxf(a1.z, 0.f);
            xT[hb + 3 * 68 + 1] = fmaxf(a1.w, 0.f);
            xT[hb + 0 * 68 + 2] = fmaxf(a2.x, 0.f);
            xT[hb + 1 * 68 + 2] = fmaxf(a2.y, 0.f);
            xT[hb + 2 * 68 + 2] = fmaxf(a2.z, 0.f);
            xT[hb + 3 * 68 + 2] = fmaxf(a2.w, 0.f);
            xT[hb + 0 * 68 + 3] = fmaxf(a3.x, 0.f);
            xT[hb + 1 * 68 + 3] = fmaxf(a3.y, 0.f);
            xT[hb + 2 * 68 + 3] = fmaxf(a3.z, 0.f);
            xT[hb + 3 * 68 + 3] = fmaxf(a3.w, 0.f);
        }
        __syncthreads();

        // layer 2
        a0 = b2v; a1 = b2v; a2 = b2v; a3 = b2v;
        #pragma unroll 8
        for (int k = 0; k < 64; k++) {
            float4 xv = *(const float4*)&xT[k * 68 + 4 * ti];
            float4 wv = *(const float4*)&Ws2[k * 64 + 4 * tj];
            fma4(a0, xv.x, wv); fma4(a1, xv.y, wv); fma4(a2, xv.z, wv); fma4(a3, xv.w, wv);
        }
        int gn0 = base + 4 * ti;
#define STORE_ROW(ai, ii)                                                                  \
        {                                                                                  \
            int gn = gn0 + (ii);                                                           \
            if (gn < n) {                                                                  \
                float dg = dinv[gn];                                                       \
                float g0 = fmaxf(ai.x, 0.f) * dg, g1 = fmaxf(ai.y, 0.f) * dg;              \
                float g2 = fmaxf(ai.z, 0.f) * dg, g3 = fmaxf(ai.w, 0.f) * dg;              \
                ushort4 hv, lv;                                                            \
                hv.x = f2bf(g0); lv.x = f2bf(g0 - bf2f(hv.x));                             \
                hv.y = f2bf(g1); lv.y = f2bf(g1 - bf2f(hv.y));                             \
                hv.z = f2bf(g2); lv.z = f2bf(g2 - bf2f(hv.z));                             \
                hv.w = f2bf(g3); lv.w = f2bf(g3 - bf2f(hv.w));                             \
                *(ushort4*)&Ghi[(size_t)gn * TS + 4 * tj] = hv;                            \
                *(ushort4*)&Glo[(size_t)gn * GS + 4 * tj] = lv;                            \
            }                                                                              \
        }
        STORE_ROW(a0, 0) STORE_ROW(a1, 1) STORE_ROW(a2, 2) STORE_ROW(a3, 3)
#undef STORE_ROW
    }
}

// ---------------- fold thetas into Wm1; emit split-bf16 TRANSPOSED weights ----------------
// Wt_hi[j][q] = bf16(Wm1p[q][j]); Wt_lo[j][q] = bf16(Wm1p[q][j] - hi).  q = k*64+h (0..255), j = out col (0..63)
__global__ void wm1p_k(const float* __restrict__ thetas, const float* __restrict__ Wm1,
                       unsigned short* __restrict__ Wth, unsigned short* __restrict__ Wtl) {
    int idx = blockIdx.x * blockDim.x + threadIdx.x;   // 16384 total
    if (idx >= 16384) return;
    int j = idx & 63;
    int q = idx >> 6;      // k*64 + h
    int k = q >> 6;
    int hh = q & 63;
    float a = 0.f;
    for (int c = 0; c < 4; c++) a += thetas[c * 4 + k] * Wm1[(c * 64 + hh) * 64 + j];
    unsigned short hi = f2bf(a);
    float r = a - bf2f(hi);
    Wth[j * 256 + q] = hi;
    Wtl[j * 256 + q] = f2bf(r);
}

// ---------------- propagation in g-space: g_out = g_in - dinv^2 * CSR_gather(ghi) ----------------
// R9-shape gather: contiguous 128B rows, plain coalesced loads, 2 nodes/wave x 8-deep.
__global__ __launch_bounds__(256) void prop_k(
        const unsigned short* __restrict__ TinHi,   // Ghi + s*64 (stride TS)
        const unsigned short* __restrict__ TinLo,   // Glo + s*64 (stride GS)
        unsigned short* __restrict__ ToutHi,        // Ghi + (s+1)*64 (stride TS)
        unsigned short* __restrict__ ToutLo,        // Glo + (s+1)*64 (stride GS)
        const int* __restrict__ rowp, const int* __restrict__ colb,
        const float* __restrict__ dinv, int n, int writeLo) {
    int w = (blockIdx.x * blockDim.x + threadIdx.x) >> 6;
    int lane = threadIdx.x & 63;
    int nA = 2 * w, nB = 2 * w + 1;
    if (nA >= n) return;
    bool hasB = (nB < n);
    int eA = rowp[nA], endA = rowp[nA + 1];
    int eB = 0, endB = 0;
    if (hasB) { eB = rowp[nB]; endB = rowp[nB + 1]; }
    float a0 = 0.f, a1 = 0.f, b0 = 0.f, b1 = 0.f;
    // joint main loop: 16 outstanding gathers (8 per node)
    while (eA + 7 < endA && eB + 7 < endB) {
        int sA0 = colb[eA],     sA1 = colb[eA + 1], sA2 = colb[eA + 2], sA3 = colb[eA + 3];
        int sA4 = colb[eA + 4], sA5 = colb[eA + 5], sA6 = colb[eA + 6], sA7 = colb[eA + 7];
        int sB0 = colb[eB],     sB1 = colb[eB + 1], sB2 = colb[eB + 2], sB3 = colb[eB + 3];
        int sB4 = colb[eB + 4], sB5 = colb[eB + 5], sB6 = colb[eB + 6], sB7 = colb[eB + 7];
        float fA0 = bf2f(TinHi[(size_t)sA0 * TS + lane]);
        float fA1 = bf2f(TinHi[(size_t)sA1 * TS + lane]);
        float fA2 = bf2f(TinHi[(size_t)sA2 * TS + lane]);
        float fA3 = bf2f(TinHi[(size_t)sA3 * TS + lane]);
        float fA4 = bf2f(TinHi[(size_t)sA4 * TS + lane]);
        float fA5 = bf2f(TinHi[(size_t)sA5 * TS + lane]);
        float fA6 = bf2f(TinHi[(size_t)sA6 * TS + lane]);
        float fA7 = bf2f(TinHi[(size_t)sA7 * TS + lane]);
        float fB0 = bf2f(TinHi[(size_t)sB0 * TS + lane]);
        float fB1 = bf2f(TinHi[(size_t)sB1 * TS + lane]);
        float fB2 = bf2f(TinHi[(size_t)sB2 * TS + lane]);
        float fB3 = bf2f(TinHi[(size_t)sB3 * TS + lane]);
        float fB4 = bf2f(TinHi[(size_t)sB4 * TS + lane]);
        float fB5 = bf2f(TinHi[(size_t)sB5 * TS + lane]);
        float fB6 = bf2f(TinHi[(size_t)sB6 * TS + lane]);
        float fB7 = bf2f(TinHi[(size_t)sB7 * TS + lane]);
        a0 += (fA0 + fA2) + (fA4 + fA6);
        a1 += (fA1 + fA3) + (fA5 + fA7);
        b0 += (fB0 + fB2) + (fB4 + fB6);
        b1 += (fB1 + fB3) + (fB5 + fB7);
        eA += 8; eB += 8;
    }
    while (eA + 3 < endA) {
        int s0 = colb[eA], s1 = colb[eA + 1], s2 = colb[eA + 2], s3 = colb[eA + 3];
        float f0 = bf2f(TinHi[(size_t)s0 * TS + lane]);
        float f1 = bf2f(TinHi[(size_t)s1 * TS + lane]);
        float f2 = bf2f(TinHi[(size_t)s2 * TS + lane]);
        float f3 = bf2f(TinHi[(size_t)s3 * TS + lane]);
        a0 += f0 + f2; a1 += f1 + f3;
        eA += 4;
    }
    while (eB + 3 < endB) {
        int s0 = colb[eB], s1 = colb[eB + 1], s2 = colb[eB + 2], s3 = colb[eB + 3];
        float f0 = bf2f(TinHi[(size_t)s0 * TS + lane]);
        float f1 = bf2f(TinHi[(size_t)s1 * TS + lane]);
        float f2 = bf2f(TinHi[(size_t)s2 * TS + lane]);
        float f3 = bf2f(TinHi[(size_t)s3 * TS + lane]);
        b0 += f0 + f2; b1 += f1 + f3;
        eB += 4;
    }
    for (; eA < endA; ++eA) a0 += bf2f(TinHi[(size_t)colb[eA] * TS + lane]);
    for (; eB < endB; ++eB) b0 += bf2f(TinHi[(size_t)colb[eB] * TS + lane]);

    {
        float acc = a0 + a1;
        float dg = dinv[nA];
        float gin = bf2f(TinHi[(size_t)nA * TS + lane]) + bf2f(TinLo[(size_t)nA * GS + lane]);
        float go = gin - dg * dg * acc;
        unsigned short hi = f2bf(go);
        ToutHi[(size_t)nA * TS + lane] = hi;
        if (writeLo) ToutLo[(size_t)nA * GS + lane] = f2bf(go - bf2f(hi));
    }
    if (hasB) {
        float acc = b0 + b1;
        float dg = dinv[nB];
        float gin = bf2f(TinHi[(size_t)nB * TS + lane]) + bf2f(TinLo[(size_t)nB * GS + lane]);
        float go = gin - dg * dg * acc;
        unsigned short hi = f2bf(go);
        ToutHi[(size_t)nB * TS + lane] = hi;
        if (writeLo) ToutLo[(size_t)nB * GS + lane] = f2bf(go - bf2f(hi));
    }
}

// ---------------- final (MFMA): out = relu(s*(Ghi_row @ (Whi+Wlo)) + bm1) @ Wm2 + bm2 ----------------
// 512 threads = 8 waves = 2 row-halves x 4 col-tiles; one 128-row tile per block.
__global__ __launch_bounds__(512, 4) void final_k(const unsigned short* __restrict__ Tcat,
        const float* __restrict__ dinv,
        const unsigned short* __restrict__ Wth, const unsigned short* __restrict__ Wtl,
        const float* __restrict__ bm1, const float* __restrict__ Wm2,
        const float* __restrict__ bm2, float* __restrict__ out, int n) {
    __shared__ float Lp[4][128][2];   // per-col-tile partial (o0,o1) per row
    int tid = threadIdx.x;
    int w = tid >> 6, l = tid & 63;
    int cw = w & 3, half = w >> 2;
    int colg = 16 * cw + (l & 15);    // global output column 0..63
    int krow = (l >> 4) * 8;          // k-offset within a 32-wide k-step (B/A frag layout)

    // preload B fragments: b[ks] covers k in [ks*32, ks*32+32)
    short8v bhi[8], blo[8];
    #pragma unroll
    for (int ks = 0; ks < 8; ks++) {
        bhi[ks] = *(const short8v*)&Wth[colg * 256 + ks * 32 + krow];
        blo[ks] = *(const short8v*)&Wtl[colg * 256 + ks * 32 + krow];
    }
    float bm1c = bm1[colg];
    float w2x = Wm2[colg * 2 + 0], w2y = Wm2[colg * 2 + 1];

    int gbase = blockIdx.x * 128 + half * 64;
    const unsigned short* abase = &Tcat[(size_t)(gbase + (l & 15)) * TS + krow];

    for (int rt = 0; rt < 4; rt++) {
        f32x4 acc = {0.f, 0.f, 0.f, 0.f};
        const unsigned short* ap = abase + (size_t)rt * 16 * TS;
        #pragma unroll
        for (int ks = 0; ks < 8; ks++) {
            short8v a = *(const short8v*)(ap + ks * 32);
            acc = __builtin_amdgcn_mfma_f32_16x16x32_bf16(a, bhi[ks], acc, 0, 0, 0);
            acc = __builtin_amdgcn_mfma_f32_16x16x32_bf16(a, blo[ks], acc, 0, 0, 0);
        }
        // epilogue: C layout col=lane&15, row=(lane>>4)*4+reg (verified m89/m91)
        #pragma unroll
        for (int i = 0; i < 4; i++) {
            int rl = half * 64 + rt * 16 + (l >> 4) * 4 + i;     // row within 128-tile
            int grow = blockIdx.x * 128 + rl;
            float s = (grow < n) ? (1.0f / dinv[grow]) : 0.f;
            float h = fmaxf(fmaf(acc[i], s, bm1c), 0.f);
            float q0 = h * w2x, q1 = h * w2y;
            q0 += __shfl_xor(q0, 1); q1 += __shfl_xor(q1, 1);
            q0 += __shfl_xor(q0, 2); q1 += __shfl_xor(q1, 2);
            q0 += __shfl_xor(q0, 4); q1 += __shfl_xor(q1, 4);
            q0 += __shfl_xor(q0, 8); q1 += __shfl_xor(q1, 8);
            if ((l & 15) == 0) {
                Lp[cw][rl][0] = q0;
                Lp[cw][rl][1] = q1;
            }
        }
    }
    __syncthreads();
    if (tid < 256) {
        int r = tid >> 1, ch = tid & 1;
        int grow = blockIdx.x * 128 + r;
        if (grow < n) {
            float v = Lp[0][r][ch] + Lp[1][r][ch] + Lp[2][r][ch] + Lp[3][r][ch] + bm2[ch];
            out[grow * 2 + ch] = v;
        }
    }
}

extern "C" void kernel_launch(void* const* d_in, const int* in_sizes, int n_in,
                              void* d_out, int out_size, void* d_ws, size_t ws_size,
                              hipStream_t stream) {
    const float* x      = (const float*)d_in[0];
    const int*   src    = (const int*)d_in[1];
    const int*   dst    = (const int*)d_in[2];
    const float* thetas = (const float*)d_in[3];
    const float* W1     = (const float*)d_in[4];
    const float* b1     = (const float*)d_in[5];
    const float* W2     = (const float*)d_in[6];
    const float* b2     = (const float*)d_in[7];
    const float* Wm1    = (const float*)d_in[8];
    const float* bm1    = (const float*)d_in[9];
    const float* Wm2    = (const float*)d_in[10];
    const float* bm2    = (const float*)d_in[11];
    float* out = (float*)d_out;

    int n = in_sizes[0] / 64;
    int E = in_sizes[1];
    int ntiles  = (n + 63) / 64;       // mlp tiles (64 nodes)
    int ntiles2 = (n + 127) / 128;     // final tiles (128 nodes)
    int NB = (n + 255) / 256;          // coarse buckets (NB <= 512, n <= 131072)

    // workspace layout:
    unsigned short* Glo = (unsigned short*)d_ws;      // n*GS bf16 lo-slices 0..2 (38.4 MB)
    float* dinv  = (float*)(Glo + (size_t)n * GS);    // n
    int*   rowp  = (int*)(dinv + n);                  // n+1
    int*   colb  = rowp + (n + 1);                    // E
    size_t woff = (((size_t)(colb + E) - (size_t)d_ws) + 15) & ~(size_t)15;
    unsigned short* Wth = (unsigned short*)((char*)d_ws + woff);
    unsigned short* Wtl = Wth + 16384;
    int*   gcnt  = (int*)(Wtl + 16384);               // NB
    int*   bbase = gcnt + NB;                         // NB
    // union region (256B aligned): pairs (part1..csr2) then Ghi (mlp onward)
    size_t uoff = (((size_t)(bbase + NB) - (size_t)d_ws) + 255) & ~(size_t)255;
    unsigned int*   pairs = (unsigned int*)((char*)d_ws + uoff);      // NB*BCAP2 u32 (~7.2MB)
    unsigned short* Ghi   = (unsigned short*)pairs;                   // ntiles2*128*TS u16 (~51.3MB)

    int nchunksP = (E + CHUNK - 1) / CHUNK;

    zero_k<<<4, 256, 0, stream>>>(gcnt, NB);
    part1_k<<<nchunksP, 256, 0, stream>>>(src, dst, gcnt, pairs, E, NB);
    bscan_k<<<1, 512, 0, stream>>>(gcnt, bbase, rowp, NB, E, n);
    csr2_k<<<NB, 256, 0, stream>>>(gcnt, pairs, bbase, rowp, colb, dinv, n);

    // NOTE: Ghi aliases pairs — mlp_k (first Ghi writer) runs only after csr2_k (last pairs reader)
    mlp_k<<<768, 256, 0, stream>>>(x, W1, b1, W2, b2, dinv, Ghi, Glo, n, ntiles);
    wm1p_k<<<64, 256, 0, stream>>>(thetas, Wm1, Wth, Wtl);

    // hop s: g-space recurrence; hi slices in Ghi (s*64), lo slices in Glo (s*64, s<3)
    int nwaves = (n + 1) / 2;
    int pblocks = ((size_t)nwaves * 64 + 255) / 256;
    prop_k<<<pblocks, 256, 0, stream>>>(
        Ghi + 0 * 64, Glo + 0 * 64, Ghi + 1 * 64, Glo + 1 * 64, rowp, colb, dinv, n, 1);
    prop_k<<<pblocks, 256, 0, stream>>>(
        Ghi + 1 * 64, Glo + 1 * 64, Ghi + 2 * 64, Glo + 2 * 64, rowp, colb, dinv, n, 1);
    prop_k<<<pblocks, 256, 0, stream>>>(
        Ghi + 2 * 64, Glo + 2 * 64, Ghi + 3 * 64, Glo + 2 * 64, rowp, colb, dinv, n, 0);

    final_k<<<ntiles2, 512, 0, stream>>>(Ghi, dinv, Wth, Wtl, bm1, Wm2, bm2, out, n);
}

// Round 14
// 277.276 us; speedup vs baseline: 2.8830x; 1.0486x over previous
//
#include <hip/hip_runtime.h>
#include <math.h>

#define TS  256       // Ghi: 4 bf16 slices of 64 per node, k-major (slice k at offset k*64)
#define GS  192       // Glo: 3 bf16 lo-slices of 64 per node (slices 0..2)
#define BCAP2 4608    // bucket capacity (avg 4096 for E=1.6M, NB=391; 8-sigma margin)
#define CHUNK 4096    // edges per part1 block

typedef __attribute__((ext_vector_type(8))) short short8v;   // 8 bf16 (4 VGPRs) MFMA operand
typedef __attribute__((ext_vector_type(4))) float f32x4;     // MFMA accumulator

__device__ __forceinline__ unsigned short f2bf(float f) {
    unsigned int u = __builtin_bit_cast(unsigned int, f);
    u += 0x7fff + ((u >> 16) & 1);   // round-to-nearest-even
    return (unsigned short)(u >> 16);
}
__device__ __forceinline__ float bf2f(unsigned short s) {
    return __builtin_bit_cast(float, ((unsigned int)s) << 16);
}
__device__ __forceinline__ void fma4(float4& a, float s, const float4& b) {
    a.x = fmaf(s, b.x, a.x);
    a.y = fmaf(s, b.y, a.y);
    a.z = fmaf(s, b.z, a.z);
    a.w = fmaf(s, b.w, a.w);
}

// ---------------- utility ----------------
__global__ void zero_k(int* __restrict__ p, int n) {
    int i = blockIdx.x * blockDim.x + threadIdx.x;
    int st = gridDim.x * blockDim.x;
    for (; i < n; i += st) p[i] = 0;
}

// ---------------- CSR build, two-level dense-write ----------------
// part1: chunk-local histogram -> bulk reserve -> dense-ish packed writes.
// bucket = dst>>8 (256 nodes); packed word = src | (dst&255)<<17  (needs n <= 131072)
__global__ __launch_bounds__(256) void part1_k(const int* __restrict__ src,
        const int* __restrict__ dst, int* __restrict__ gcnt,
        unsigned int* __restrict__ pairs, int E, int NB) {
    __shared__ int lcnt[512];
    __shared__ int lbase[512];
    __shared__ int lpos[512];
    int tid = threadIdx.x;
    int base = blockIdx.x * CHUNK;
    int m = E - base; if (m > CHUNK) m = CHUNK;
    for (int b = tid; b < NB; b += 256) { lcnt[b] = 0; lpos[b] = 0; }
    __syncthreads();
    for (int i = tid; i < m; i += 256)
        atomicAdd(&lcnt[dst[base + i] >> 8], 1);
    __syncthreads();
    for (int b = tid; b < NB; b += 256)
        lbase[b] = (lcnt[b] > 0) ? atomicAdd(&gcnt[b], lcnt[b]) : 0;
    __syncthreads();
    for (int i = tid; i < m; i += 256) {
        int s = src[base + i], d = dst[base + i];
        int b = d >> 8;
        int p = atomicAdd(&lpos[b], 1);
        int idx = lbase[b] + p;
        if (idx < BCAP2)
            pairs[(size_t)b * BCAP2 + idx] = (unsigned int)s | ((unsigned int)(d & 255) << 17);
    }
}

// exclusive scan of bucket sizes (NB <= 512), single block of 512; also writes rowp[n]=E
__global__ __launch_bounds__(512) void bscan_k(const int* __restrict__ gcnt,
        int* __restrict__ bbase, int* __restrict__ rowp, int NB, int E, int n) {
    __shared__ int buf[512];
    int tid = threadIdx.x;
    int v = (tid < NB) ? (gcnt[tid] > BCAP2 ? BCAP2 : gcnt[tid]) : 0;
    buf[tid] = v;
    __syncthreads();
    int x = v;
    for (int off = 1; off < 512; off <<= 1) {
        int t = (tid >= off) ? buf[tid - off] : 0;
        __syncthreads();
        x += t;
        buf[tid] = x;
        __syncthreads();
    }
    if (tid < NB) bbase[tid] = x - v;
    if (tid == 0) rowp[n] = E;
}

// csr2: per-bucket histogram + scan + rowp/dinv + dense colb fill (contiguous 16KB window)
__global__ __launch_bounds__(256) void csr2_k(const int* __restrict__ gcnt,
        const unsigned int* __restrict__ pairs, const int* __restrict__ bbase,
        int* __restrict__ rowp, int* __restrict__ colb, float* __restrict__ dinv, int n) {
    int b = blockIdx.x;
    int tid = threadIdx.x;
    int cntb = gcnt[b]; if (cntb > BCAP2) cntb = BCAP2;
    const unsigned int* pb = pairs + (size_t)b * BCAP2;
    __shared__ int c[256];
    __shared__ int sc[256];
    __shared__ int lpos[256];
    c[tid] = 0; lpos[tid] = 0;
    __syncthreads();
    for (int i = tid; i < cntb; i += 256)
        atomicAdd(&c[pb[i] >> 17], 1);
    __syncthreads();
    int v = c[tid];
    sc[tid] = v;
    __syncthreads();
    int x = v;
    for (int off = 1; off < 256; off <<= 1) {
        int t = (tid >= off) ? sc[tid - off] : 0;
        __syncthreads();
        x += t;
        sc[tid] = x;
        __syncthreads();
    }
    int ex = x - v;                 // exclusive within-bucket start
    sc[tid] = ex;
    int node = b * 256 + tid;
    if (node < n) {
        rowp[node] = bbase[b] + ex;
        dinv[node] = 1.0f / sqrtf((float)(v > 1 ? v : 1));
    }
    __syncthreads();                // sc (exclusive) visible to all
    for (int i = tid; i < cntb; i += 256) {
        unsigned int pk = pb[i];
        int j = pk >> 17;
        int p = atomicAdd(&lpos[j], 1);
        colb[bbase[b] + sc[j] + p] = (int)(pk & 0x1FFFF);
    }
}

// ---------------- fused 2-layer MLP, register-tiled; emits g0 = h2*dinv as bf16 hi/lo pair ----------------
__global__ __launch_bounds__(256) void mlp_k(const float* __restrict__ x,
        const float* __restrict__ W1, const float* __restrict__ b1,
        const float* __restrict__ W2, const float* __restrict__ b2,
        const float* __restrict__ dinv,
        unsigned short* __restrict__ Ghi, unsigned short* __restrict__ Glo,
        int n, int ntiles) {
    __shared__ float Ws1[64 * 64];   // 16 KB, [k][j]
    __shared__ float Ws2[64 * 64];   // 16 KB
    __shared__ float xT[64 * 68];    // 17.4 KB, [k][node], stride 68 (16B-aligned rows)
    int tid = threadIdx.x;
    int ti = tid >> 4, tj = tid & 15;
    for (int idx = tid; idx < 4096; idx += 256) { Ws1[idx] = W1[idx]; Ws2[idx] = W2[idx]; }
    float4 b1v = *(const float4*)&b1[4 * tj];
    float4 b2v = *(const float4*)&b2[4 * tj];

    for (int g = blockIdx.x; g < ntiles; g += gridDim.x) {
        int base = g * 64;
        __syncthreads();   // xT free of previous tile's readers (also covers Ws staging on iter 0)
        for (int it = 0; it < 4; it++) {
            int node = ti + it * 16;
            int gn = base + node;
            float4 v = make_float4(0.f, 0.f, 0.f, 0.f);
            if (gn < n) v = *(const float4*)&x[(size_t)gn * 64 + 4 * tj];
            xT[(4 * tj + 0) * 68 + node] = v.x;
            xT[(4 * tj + 1) * 68 + node] = v.y;
            xT[(4 * tj + 2) * 68 + node] = v.z;
            xT[(4 * tj + 3) * 68 + node] = v.w;
        }
        __syncthreads();

        // layer 1
        float4 a0 = b1v, a1 = b1v, a2 = b1v, a3 = b1v;
        #pragma unroll 8
        for (int k = 0; k < 64; k++) {
            float4 xv = *(const float4*)&xT[k * 68 + 4 * ti];
            float4 wv = *(const float4*)&Ws1[k * 64 + 4 * tj];
            fma4(a0, xv.x, wv); fma4(a1, xv.y, wv); fma4(a2, xv.z, wv); fma4(a3, xv.w, wv);
        }
        __syncthreads();
        {
            int hb = (4 * tj) * 68 + 4 * ti;
            xT[hb + 0 * 68 + 0] = fmaxf(a0.x, 0.f);
            xT[hb + 1 * 68 + 0] = fmaxf(a0.y, 0.f);
            xT[hb + 2 * 68 + 0] = fmaxf(a0.z, 0.f);
            xT[hb + 3 * 68 + 0] = fmaxf(a0.w, 0.f);
            xT[hb + 0 * 68 + 1] = fmaxf(a1.x, 0.f);
            xT[hb + 1 * 68 + 1] = fmaxf(a1.y, 0.f);
            xT[hb + 2 * 68 + 1] = fmaxf(a1.z, 0.f);
            xT[hb + 3 * 68 + 1] = fmaxf(a1.w, 0.f);
            xT[hb + 0 * 68 + 2] = fmaxf(a2.x, 0.f);
            xT[hb + 1 * 68 + 2] = fmaxf(a2.y, 0.f);
            xT[hb + 2 * 68 + 2] = fmaxf(a2.z, 0.f);
            xT[hb + 3 * 68 + 2] = fmaxf(a2.w, 0.f);
            xT[hb + 0 * 68 + 3] = fmaxf(a3.x, 0.f);
            xT[hb + 1 * 68 + 3] = fmaxf(a3.y, 0.f);
            xT[hb + 2 * 68 + 3] = fmaxf(a3.z, 0.f);
            xT[hb + 3 * 68 + 3] = fmaxf(a3.w, 0.f);
        }
        __syncthreads();

        // layer 2
        a0 = b2v; a1 = b2v; a2 = b2v; a3 = b2v;
        #pragma unroll 8
        for (int k = 0; k < 64; k++) {
            float4 xv = *(const float4*)&xT[k * 68 + 4 * ti];
            float4 wv = *(const float4*)&Ws2[k * 64 + 4 * tj];
            fma4(a0, xv.x, wv); fma4(a1, xv.y, wv); fma4(a2, xv.z, wv); fma4(a3, xv.w, wv);
        }
        int gn0 = base + 4 * ti;
#define STORE_ROW(ai, ii)                                                                  \
        {                                                                                  \
            int gn = gn0 + (ii);                                                           \
            if (gn < n) {                                                                  \
                float dg = dinv[gn];                                                       \
                float g0 = fmaxf(ai.x, 0.f) * dg, g1 = fmaxf(ai.y, 0.f) * dg;              \
                float g2 = fmaxf(ai.z, 0.f) * dg, g3 = fmaxf(ai.w, 0.f) * dg;              \
                ushort4 hv, lv;                                                            \
                hv.x = f2bf(g0); lv.x = f2bf(g0 - bf2f(hv.x));                             \
                hv.y = f2bf(g1); lv.y = f2bf(g1 - bf2f(hv.y));                             \
                hv.z = f2bf(g2); lv.z = f2bf(g2 - bf2f(hv.z));                             \
                hv.w = f2bf(g3); lv.w = f2bf(g3 - bf2f(hv.w));                             \
                *(ushort4*)&Ghi[(size_t)gn * TS + 4 * tj] = hv;                            \
                *(ushort4*)&Glo[(size_t)gn * GS + 4 * tj] = lv;                            \
            }                                                                              \
        }
        STORE_ROW(a0, 0) STORE_ROW(a1, 1) STORE_ROW(a2, 2) STORE_ROW(a3, 3)
#undef STORE_ROW
    }
}

// ---------------- fold thetas into Wm1; emit split-bf16 TRANSPOSED weights ----------------
// Wt_hi[j][q] = bf16(Wm1p[q][j]); Wt_lo[j][q] = bf16(Wm1p[q][j] - hi).  q = k*64+h (0..255), j = out col (0..63)
__global__ void wm1p_k(const float* __restrict__ thetas, const float* __restrict__ Wm1,
                       unsigned short* __restrict__ Wth, unsigned short* __restrict__ Wtl) {
    int idx = blockIdx.x * blockDim.x + threadIdx.x;   // 16384 total
    if (idx >= 16384) return;
    int j = idx & 63;
    int q = idx >> 6;      // k*64 + h
    int k = q >> 6;
    int hh = q & 63;
    float a = 0.f;
    for (int c = 0; c < 4; c++) a += thetas[c * 4 + k] * Wm1[(c * 64 + hh) * 64 + j];
    unsigned short hi = f2bf(a);
    float r = a - bf2f(hi);
    Wth[j * 256 + q] = hi;
    Wtl[j * 256 + q] = f2bf(r);
}

// ---------------- propagation in g-space: g_out = g_in - dinv^2 * CSR_gather(ghi) ----------------
// R9-shape gather: contiguous 128B rows, plain coalesced loads, 2 nodes/wave x 8-deep.
__global__ __launch_bounds__(256) void prop_k(
        const unsigned short* __restrict__ TinHi,   // Ghi + s*64 (stride TS)
        const unsigned short* __restrict__ TinLo,   // Glo + s*64 (stride GS)
        unsigned short* __restrict__ ToutHi,        // Ghi + (s+1)*64 (stride TS)
        unsigned short* __restrict__ ToutLo,        // Glo + (s+1)*64 (stride GS)
        const int* __restrict__ rowp, const int* __restrict__ colb,
        const float* __restrict__ dinv, int n, int writeLo) {
    int w = (blockIdx.x * blockDim.x + threadIdx.x) >> 6;
    int lane = threadIdx.x & 63;
    int nA = 2 * w, nB = 2 * w + 1;
    if (nA >= n) return;
    bool hasB = (nB < n);
    int eA = rowp[nA], endA = rowp[nA + 1];
    int eB = 0, endB = 0;
    if (hasB) { eB = rowp[nB]; endB = rowp[nB + 1]; }
    float a0 = 0.f, a1 = 0.f, b0 = 0.f, b1 = 0.f;
    // joint main loop: 16 outstanding gathers (8 per node)
    while (eA + 7 < endA && eB + 7 < endB) {
        int sA0 = colb[eA],     sA1 = colb[eA + 1], sA2 = colb[eA + 2], sA3 = colb[eA + 3];
        int sA4 = colb[eA + 4], sA5 = colb[eA + 5], sA6 = colb[eA + 6], sA7 = colb[eA + 7];
        int sB0 = colb[eB],     sB1 = colb[eB + 1], sB2 = colb[eB + 2], sB3 = colb[eB + 3];
        int sB4 = colb[eB + 4], sB5 = colb[eB + 5], sB6 = colb[eB + 6], sB7 = colb[eB + 7];
        float fA0 = bf2f(TinHi[(size_t)sA0 * TS + lane]);
        float fA1 = bf2f(TinHi[(size_t)sA1 * TS + lane]);
        float fA2 = bf2f(TinHi[(size_t)sA2 * TS + lane]);
        float fA3 = bf2f(TinHi[(size_t)sA3 * TS + lane]);
        float fA4 = bf2f(TinHi[(size_t)sA4 * TS + lane]);
        float fA5 = bf2f(TinHi[(size_t)sA5 * TS + lane]);
        float fA6 = bf2f(TinHi[(size_t)sA6 * TS + lane]);
        float fA7 = bf2f(TinHi[(size_t)sA7 * TS + lane]);
        float fB0 = bf2f(TinHi[(size_t)sB0 * TS + lane]);
        float fB1 = bf2f(TinHi[(size_t)sB1 * TS + lane]);
        float fB2 = bf2f(TinHi[(size_t)sB2 * TS + lane]);
        float fB3 = bf2f(TinHi[(size_t)sB3 * TS + lane]);
        float fB4 = bf2f(TinHi[(size_t)sB4 * TS + lane]);
        float fB5 = bf2f(TinHi[(size_t)sB5 * TS + lane]);
        float fB6 = bf2f(TinHi[(size_t)sB6 * TS + lane]);
        float fB7 = bf2f(TinHi[(size_t)sB7 * TS + lane]);
        a0 += (fA0 + fA2) + (fA4 + fA6);
        a1 += (fA1 + fA3) + (fA5 + fA7);
        b0 += (fB0 + fB2) + (fB4 + fB6);
        b1 += (fB1 + fB3) + (fB5 + fB7);
        eA += 8; eB += 8;
    }
    while (eA + 3 < endA) {
        int s0 = colb[eA], s1 = colb[eA + 1], s2 = colb[eA + 2], s3 = colb[eA + 3];
        float f0 = bf2f(TinHi[(size_t)s0 * TS + lane]);
        float f1 = bf2f(TinHi[(size_t)s1 * TS + lane]);
        float f2 = bf2f(TinHi[(size_t)s2 * TS + lane]);
        float f3 = bf2f(TinHi[(size_t)s3 * TS + lane]);
        a0 += f0 + f2; a1 += f1 + f3;
        eA += 4;
    }
    while (eB + 3 < endB) {
        int s0 = colb[eB], s1 = colb[eB + 1], s2 = colb[eB + 2], s3 = colb[eB + 3];
        float f0 = bf2f(TinHi[(size_t)s0 * TS + lane]);
        float f1 = bf2f(TinHi[(size_t)s1 * TS + lane]);
        float f2 = bf2f(TinHi[(size_t)s2 * TS + lane]);
        float f3 = bf2f(TinHi[(size_t)s3 * TS + lane]);
        b0 += f0 + f2; b1 += f1 + f3;
        eB += 4;
    }
    for (; eA < endA; ++eA) a0 += bf2f(TinHi[(size_t)colb[eA] * TS + lane]);
    for (; eB < endB; ++eB) b0 += bf2f(TinHi[(size_t)colb[eB] * TS + lane]);

    {
        float acc = a0 + a1;
        float dg = dinv[nA];
        float gin = bf2f(TinHi[(size_t)nA * TS + lane]) + bf2f(TinLo[(size_t)nA * GS + lane]);
        float go = gin - dg * dg * acc;
        unsigned short hi = f2bf(go);
        ToutHi[(size_t)nA * TS + lane] = hi;
        if (writeLo) ToutLo[(size_t)nA * GS + lane] = f2bf(go - bf2f(hi));
    }
    if (hasB) {
        float acc = b0 + b1;
        float dg = dinv[nB];
        float gin = bf2f(TinHi[(size_t)nB * TS + lane]) + bf2f(TinLo[(size_t)nB * GS + lane]);
        float go = gin - dg * dg * acc;
        unsigned short hi = f2bf(go);
        ToutHi[(size_t)nB * TS + lane] = hi;
        if (writeLo) ToutLo[(size_t)nB * GS + lane] = f2bf(go - bf2f(hi));
    }
}

// ---------------- final (MFMA, LDS-staged): out = relu(s*(G @ (Whi+Wlo)) + bm1) @ Wm2 + bm2 ----------
// grid = 256 (1 block/CU), 512 threads, grid-stride over 128-row tiles.
// B (Wth+Wtl, 64KB) staged once per block; A-tile (64KB) staged per tile — both with
// XOR swizzle byte^=((byte>>9)&7)<<4 to kill the 512B-stride 16-way bank conflict (G4).
// Transactions: sequential A (800k unique lines) + B 256x1024 — no 4x col-wave duplication.
__global__ __launch_bounds__(512) void final_k(const unsigned short* __restrict__ Ghi,
        const float* __restrict__ dinv,
        const unsigned short* __restrict__ Wth, const unsigned short* __restrict__ Wtl,
        const float* __restrict__ bm1, const float* __restrict__ Wm2,
        const float* __restrict__ bm2, float* __restrict__ out, int n, int ntiles) {
    __shared__ unsigned short Bs[32768];   // 64 KB: hi cols 0-63 (512B each), lo at +32768B
    __shared__ unsigned short As[32768];   // 64 KB: 128 rows x 512B
    __shared__ float Lp[4][128][2];        // 4 KB: per-col-tile partial (o0,o1) per row
    int tid = threadIdx.x;
    int w = tid >> 6, l = tid & 63;
    int cw = w & 3, half = w >> 2;
    int colg = 16 * cw + (l & 15);         // global output column 0..63
    int grp = l >> 4;                      // k-subgroup 0..3

    // stage B: 4096 granules of 16B, sequential global reads, swizzled LDS writes
    for (int i = tid; i < 4096; i += 512) {
        int byte = i * 16;
        int col = byte >> 9;               // 0..127 (64..127 = lo half)
        int swz = byte ^ ((col & 7) << 4);
        uint4 v = (byte < 32768) ? *(const uint4*)((const char*)Wth + byte)
                                 : *(const uint4*)((const char*)Wtl + (byte - 32768));
        *(uint4*)((char*)Bs + swz) = v;
    }
    float bm1c = bm1[colg];
    float w2x = Wm2[colg * 2 + 0], w2y = Wm2[colg * 2 + 1];
    float bo0 = bm2[0], bo1 = bm2[1];
    __syncthreads();

    for (int g = blockIdx.x; g < ntiles; g += gridDim.x) {
        // stage A tile: 64KB sequential, swizzled
        const char* asrc = (const char*)(Ghi + (size_t)g * 128 * TS);
        for (int i = tid; i < 4096; i += 512) {
            int byte = i * 16;
            int row = byte >> 9;
            int swz = byte ^ ((row & 7) << 4);
            *(uint4*)((char*)As + swz) = *(const uint4*)(asrc + byte);
        }
        __syncthreads();   // A ready; also fences previous tile's Lp readers

        for (int rt = 0; rt < 4; rt++) {
            int arow = half * 64 + rt * 16 + (l & 15);
            int abase = arow * 512 + grp * 16;
            int axor = (arow & 7) << 4;
            int bbase = colg * 512 + grp * 16;
            int bxor = (colg & 7) << 4;
            f32x4 acc = {0.f, 0.f, 0.f, 0.f};
            #pragma unroll
            for (int ks = 0; ks < 8; ks++) {
                short8v a  = *(const short8v*)((const char*)As + ((abase + ks * 64) ^ axor));
                int bb = (bbase + ks * 64) ^ bxor;
                short8v bh = *(const short8v*)((const char*)Bs + bb);
                short8v bl = *(const short8v*)((const char*)Bs + (bb + 32768));
                acc = __builtin_amdgcn_mfma_f32_16x16x32_bf16(a, bh, acc, 0, 0, 0);
                acc = __builtin_amdgcn_mfma_f32_16x16x32_bf16(a, bl, acc, 0, 0, 0);
            }
            // epilogue: C layout col=lane&15, row=(lane>>4)*4+reg (verified m89/m91)
            #pragma unroll
            for (int i = 0; i < 4; i++) {
                int rl = half * 64 + rt * 16 + (l >> 4) * 4 + i;   // row within 128-tile
                int grow = g * 128 + rl;
                float s = (grow < n) ? (1.0f / dinv[grow]) : 0.f;
                float h = fmaxf(fmaf(acc[i], s, bm1c), 0.f);
                float q0 = h * w2x, q1 = h * w2y;
                q0 += __shfl_xor(q0, 1); q1 += __shfl_xor(q1, 1);
                q0 += __shfl_xor(q0, 2); q1 += __shfl_xor(q1, 2);
                q0 += __shfl_xor(q0, 4); q1 += __shfl_xor(q1, 4);
                q0 += __shfl_xor(q0, 8); q1 += __shfl_xor(q1, 8);
                if ((l & 15) == 0) {
                    Lp[cw][rl][0] = q0;
                    Lp[cw][rl][1] = q1;
                }
            }
        }
        __syncthreads();   // Lp complete
        if (tid < 256) {
            int r = tid >> 1, ch = tid & 1;
            int grow = g * 128 + r;
            if (grow < n) {
                float v = Lp[0][r][ch] + Lp[1][r][ch] + Lp[2][r][ch] + Lp[3][r][ch]
                        + ((ch == 0) ? bo0 : bo1);
                out[grow * 2 + ch] = v;
            }
        }
        // next iteration's A-load barrier separates Lp readers from next Lp writers
    }
}

extern "C" void kernel_launch(void* const* d_in, const int* in_sizes, int n_in,
                              void* d_out, int out_size, void* d_ws, size_t ws_size,
                              hipStream_t stream) {
    const float* x      = (const float*)d_in[0];
    const int*   src    = (const int*)d_in[1];
    const int*   dst    = (const int*)d_in[2];
    const float* thetas = (const float*)d_in[3];
    const float* W1     = (const float*)d_in[4];
    const float* b1     = (const float*)d_in[5];
    const float* W2     = (const float*)d_in[6];
    const float* b2     = (const float*)d_in[7];
    const float* Wm1    = (const float*)d_in[8];
    const float* bm1    = (const float*)d_in[9];
    const float* Wm2    = (const float*)d_in[10];
    const float* bm2    = (const float*)d_in[11];
    float* out = (float*)d_out;

    int n = in_sizes[0] / 64;
    int E = in_sizes[1];
    int ntiles  = (n + 63) / 64;       // mlp tiles (64 nodes)
    int ntiles2 = (n + 127) / 128;     // final tiles (128 nodes)
    int NB = (n + 255) / 256;          // coarse buckets (NB <= 512, n <= 131072)

    // workspace layout:
    unsigned short* Glo = (unsigned short*)d_ws;      // n*GS bf16 lo-slices 0..2 (38.4 MB)
    float* dinv  = (float*)(Glo + (size_t)n * GS);    // n
    int*   rowp  = (int*)(dinv + n);                  // n+1
    int*   colb  = rowp + (n + 1);                    // E
    size_t woff = (((size_t)(colb + E) - (size_t)d_ws) + 15) & ~(size_t)15;
    unsigned short* Wth = (unsigned short*)((char*)d_ws + woff);
    unsigned short* Wtl = Wth + 16384;
    int*   gcnt  = (int*)(Wtl + 16384);               // NB
    int*   bbase = gcnt + NB;                         // NB
    // union region (256B aligned): pairs (part1..csr2) then Ghi (mlp onward)
    size_t uoff = (((size_t)(bbase + NB) - (size_t)d_ws) + 255) & ~(size_t)255;
    unsigned int*   pairs = (unsigned int*)((char*)d_ws + uoff);      // NB*BCAP2 u32 (~7.2MB)
    unsigned short* Ghi   = (unsigned short*)pairs;                   // ntiles2*128*TS u16 (~51.3MB)

    int nchunksP = (E + CHUNK - 1) / CHUNK;

    zero_k<<<4, 256, 0, stream>>>(gcnt, NB);
    part1_k<<<nchunksP, 256, 0, stream>>>(src, dst, gcnt, pairs, E, NB);
    bscan_k<<<1, 512, 0, stream>>>(gcnt, bbase, rowp, NB, E, n);
    csr2_k<<<NB, 256, 0, stream>>>(gcnt, pairs, bbase, rowp, colb, dinv, n);

    // NOTE: Ghi aliases pairs — mlp_k (first Ghi writer) runs only after csr2_k (last pairs reader)
    mlp_k<<<768, 256, 0, stream>>>(x, W1, b1, W2, b2, dinv, Ghi, Glo, n, ntiles);
    wm1p_k<<<64, 256, 0, stream>>>(thetas, Wm1, Wth, Wtl);

    // hop s: g-space recurrence; hi slices in Ghi (s*64), lo slices in Glo (s*64, s<3)
    int nwaves = (n + 1) / 2;
    int pblocks = ((size_t)nwaves * 64 + 255) / 256;
    prop_k<<<pblocks, 256, 0, stream>>>(
        Ghi + 0 * 64, Glo + 0 * 64, Ghi + 1 * 64, Glo + 1 * 64, rowp, colb, dinv, n, 1);
    prop_k<<<pblocks, 256, 0, stream>>>(
        Ghi + 1 * 64, Glo + 1 * 64, Ghi + 2 * 64, Glo + 2 * 64, rowp, colb, dinv, n, 1);
    prop_k<<<pblocks, 256, 0, stream>>>(
        Ghi + 2 * 64, Glo + 2 * 64, Ghi + 3 * 64, Glo + 2 * 64, rowp, colb, dinv, n, 0);

    int fgrid = ntiles2 < 256 ? ntiles2 : 256;
    final_k<<<fgrid, 512, 0, stream>>>(Ghi, dinv, Wth, Wtl, bm1, Wm2, bm2, out, n, ntiles2);
}